// Round 1
// baseline (396.786 us; speedup 1.0000x reference)
//
#include <hip/hip_runtime.h>

#define BB 32
#define CC 384
#define TT 512
#define MAX_FRAMES 6656   // T * 13

// ---------------- Kernel 1: repeat counts + inclusive scan ----------------
// grid = B blocks, TT threads. cum[b][t] = inclusive cumsum of r.
__global__ void lr_scan_kernel(const float* __restrict__ duration,
                               int* __restrict__ cum,
                               float* __restrict__ fl_out) {
    __shared__ int buf[TT];
    const int b = blockIdx.x;
    const int t = threadIdx.x;
    const float d = duration[b * TT + t];
    const float fr = 44100.0f * d;
    float rf;
    if (fr - 1024.0f > 0.0f) {
        rf = fmaxf((fr - 1024.0f) * (1.0f / 256.0f), 1.0f);
    } else {
        rf = (d == 0.0f) ? 0.0f : 1.0f;
    }
    buf[t] = (int)rf;   // astype(int32): truncation toward zero
    __syncthreads();
    // Hillis-Steele inclusive scan over 512 elements
    for (int off = 1; off < TT; off <<= 1) {
        int add = (t >= off) ? buf[t - off] : 0;
        __syncthreads();
        buf[t] += add;
        __syncthreads();
    }
    cum[b * TT + t] = buf[t];
    if (t == TT - 1) fl_out[b] = (float)buf[t];  // frame_lengths (read back as f32)
}

// ---------------- Kernel 2: searchsorted + pitch ----------------
// grid = (MAX_FRAMES/256, B), 256 threads. tok[b][p] = upper_bound(cum[b], p), clamped.
__global__ void lr_tok_pitch_kernel(const float* __restrict__ notepitch,
                                    const int* __restrict__ cum,
                                    int* __restrict__ tok_out,
                                    float* __restrict__ pitch_out) {
    __shared__ int scum[TT];
    const int b = blockIdx.y;
    const int p = blockIdx.x * 256 + threadIdx.x;
    for (int i = threadIdx.x; i < TT; i += 256) scum[i] = cum[b * TT + i];
    __syncthreads();
    const int fl = scum[TT - 1];
    // searchsorted side='right': first index with scum[idx] > p
    int lo = 0, hi = TT;
    while (lo < hi) {
        int mid = (lo + hi) >> 1;
        if (scum[mid] <= p) lo = mid + 1; else hi = mid;
    }
    int tk = lo;
    if (tk > TT - 1) tk = TT - 1;
    tok_out[b * MAX_FRAMES + p] = tk;
    float pv = 0.0f;
    if (p < fl) pv = (float)(int)notepitch[b * TT + tk];
    pitch_out[b * MAX_FRAMES + p] = pv;
}

// ---------------- Kernel 3: expand x ----------------
// grid = (ceil(MAX_FRAMES/1024), C, B), 256 threads, 4 frames (float4) per thread.
__global__ void lr_expand_kernel(const float* __restrict__ x,
                                 const int* __restrict__ cum,
                                 const int* __restrict__ tok,
                                 float* __restrict__ out) {
    const int b = blockIdx.z;
    const int c = blockIdx.y;
    const int p0 = (blockIdx.x * 256 + threadIdx.x) * 4;
    if (p0 >= MAX_FRAMES) return;
    const int fl = cum[b * TT + (TT - 1)];   // scalar, L2-cached
    const int4 tk = *(const int4*)(tok + b * MAX_FRAMES + p0);
    const float* __restrict__ xrow = x + ((size_t)(b * CC + c)) * TT;
    float4 v;
    v.x = (p0 + 0 < fl) ? xrow[tk.x] : 0.0f;
    v.y = (p0 + 1 < fl) ? xrow[tk.y] : 0.0f;
    v.z = (p0 + 2 < fl) ? xrow[tk.z] : 0.0f;
    v.w = (p0 + 3 < fl) ? xrow[tk.w] : 0.0f;
    *(float4*)(out + ((size_t)(b * CC + c)) * MAX_FRAMES + p0) = v;
}

extern "C" void kernel_launch(void* const* d_in, const int* in_sizes, int n_in,
                              void* d_out, int out_size, void* d_ws, size_t ws_size,
                              hipStream_t stream) {
    const float* x         = (const float*)d_in[0];  // (B, C, T)
    const float* notepitch = (const float*)d_in[1];  // (B, T)
    const float* duration  = (const float*)d_in[2];  // (B, T)
    // d_in[3] = x_lengths — unused by the reference computation

    float* out       = (float*)d_out;                          // (B, C, MAX_FRAMES)
    float* pitch_out = out + (size_t)BB * CC * MAX_FRAMES;     // (B, MAX_FRAMES)
    float* fl_out    = pitch_out + (size_t)BB * MAX_FRAMES;    // (B,)

    int* cum = (int*)d_ws;           // B*T ints = 64 KB
    int* tok = cum + BB * TT;        // B*MAX_FRAMES ints = 832 KB

    lr_scan_kernel<<<BB, TT, 0, stream>>>(duration, cum, fl_out);

    dim3 gb(MAX_FRAMES / 256, BB);
    lr_tok_pitch_kernel<<<gb, 256, 0, stream>>>(notepitch, cum, tok, pitch_out);

    dim3 gc((MAX_FRAMES / 4 + 255) / 256, CC, BB);
    lr_expand_kernel<<<gc, 256, 0, stream>>>(x, cum, tok, out);
}

// Round 3
// 353.092 us; speedup vs baseline: 1.1237x; 1.1237x over previous
//
#include <hip/hip_runtime.h>

#define BB 32
#define CC 384
#define TT 512
#define MAXF 6656      // T * 13
#define CG 8           // channels per block
#define NCHUNK 7       // ceil(6656 / 1024), last chunk is half

// ---------------- Kernel 1: repeat counts + inclusive scan ----------------
__global__ void lr_scan_kernel(const float* __restrict__ duration,
                               int* __restrict__ cum,
                               float* __restrict__ fl_out) {
    __shared__ int buf[TT];
    const int b = blockIdx.x;
    const int t = threadIdx.x;
    const float d = duration[b * TT + t];
    const float fr = 44100.0f * d;
    float rf;
    if (fr - 1024.0f > 0.0f) {
        rf = fmaxf((fr - 1024.0f) * (1.0f / 256.0f), 1.0f);
    } else {
        rf = (d == 0.0f) ? 0.0f : 1.0f;
    }
    buf[t] = (int)rf;   // truncation toward zero, matches astype(int32)
    __syncthreads();
    for (int off = 1; off < TT; off <<= 1) {
        int add = (t >= off) ? buf[t - off] : 0;
        __syncthreads();
        buf[t] += add;
        __syncthreads();
    }
    cum[b * TT + t] = buf[t];
    if (t == TT - 1) fl_out[b] = (float)buf[t];
}

// ---------------- Kernel 2: fused search + expand + pitch ----------------
// grid = (CC/CG, BB), 256 threads. Block stages cum + 8 x-rows in LDS,
// searches once per 4-frame group, gathers from LDS for all 8 channels.
__global__ __launch_bounds__(256) void lr_expand_kernel(
        const float* __restrict__ x,
        const float* __restrict__ notepitch,
        const int* __restrict__ cum,
        float* __restrict__ out,
        float* __restrict__ pitch_out) {
    __shared__ int   scum[TT];
    __shared__ float xs[CG * TT];
    __shared__ float snp[TT];

    const int b   = blockIdx.y;
    const int cg  = blockIdx.x;
    const int tid = threadIdx.x;
    const bool do_pitch = (cg == 0);

    for (int i = tid; i < TT; i += 256) scum[i] = cum[b * TT + i];
    {
        const float4* src = (const float4*)(x + ((size_t)(b * CC + cg * CG)) * TT);
        float4* dst = (float4*)xs;
        #pragma unroll
        for (int i = 0; i < (CG * TT / 4) / 256; ++i)
            dst[i * 256 + tid] = src[i * 256 + tid];
    }
    if (do_pitch)
        for (int i = tid; i < TT; i += 256) snp[i] = notepitch[b * TT + i];
    __syncthreads();

    const int fl = scum[TT - 1];

    for (int ch = 0; ch < NCHUNK; ++ch) {
        const int p0 = ch * 1024 + tid * 4;
        if (p0 >= MAXF) continue;    // only chunk 6, tid >= 128

        // searchsorted side='right': first idx with scum[idx] > p0.
        // NOTE: must iterate until lo==hi (10 worst-case steps for n=512);
        // a fixed 9-step unroll leaves a size-1 interval -> off-by-one (R2 bug).
        int lo = 0, hi = TT;
        while (lo < hi) {
            int mid = (lo + hi) >> 1;
            if (scum[mid] <= p0) lo = mid + 1; else hi = mid;
        }
        int t0 = lo;
        int t1 = t0; while (t1 < TT && scum[t1] <= p0 + 1) ++t1;
        int t2 = t1; while (t2 < TT && scum[t2] <= p0 + 2) ++t2;
        int t3 = t2; while (t3 < TT && scum[t3] <= p0 + 3) ++t3;
        const int u0 = min(t0, TT - 1), u1 = min(t1, TT - 1);
        const int u2 = min(t2, TT - 1), u3 = min(t3, TT - 1);
        const bool m0 = p0 < fl, m1 = p0 + 1 < fl, m2 = p0 + 2 < fl, m3 = p0 + 3 < fl;

        #pragma unroll
        for (int c = 0; c < CG; ++c) {
            const float* xr = xs + c * TT;
            float4 v;
            v.x = m0 ? xr[u0] : 0.0f;
            v.y = m1 ? xr[u1] : 0.0f;
            v.z = m2 ? xr[u2] : 0.0f;
            v.w = m3 ? xr[u3] : 0.0f;
            *(float4*)(out + ((size_t)(b * CC + cg * CG + c)) * MAXF + p0) = v;
        }
        if (do_pitch) {
            float4 pv;
            pv.x = m0 ? (float)(int)snp[u0] : 0.0f;
            pv.y = m1 ? (float)(int)snp[u1] : 0.0f;
            pv.z = m2 ? (float)(int)snp[u2] : 0.0f;
            pv.w = m3 ? (float)(int)snp[u3] : 0.0f;
            *(float4*)(pitch_out + (size_t)b * MAXF + p0) = pv;
        }
    }
}

extern "C" void kernel_launch(void* const* d_in, const int* in_sizes, int n_in,
                              void* d_out, int out_size, void* d_ws, size_t ws_size,
                              hipStream_t stream) {
    const float* x         = (const float*)d_in[0];  // (B, C, T)
    const float* notepitch = (const float*)d_in[1];  // (B, T)
    const float* duration  = (const float*)d_in[2];  // (B, T)
    // d_in[3] = x_lengths — unused by the reference computation

    float* out       = (float*)d_out;                       // (B, C, MAXF)
    float* pitch_out = out + (size_t)BB * CC * MAXF;        // (B, MAXF)
    float* fl_out    = pitch_out + (size_t)BB * MAXF;       // (B,)

    int* cum = (int*)d_ws;   // B*T ints = 64 KB

    lr_scan_kernel<<<BB, TT, 0, stream>>>(duration, cum, fl_out);

    dim3 g2(CC / CG, BB);    // 48 x 32 = 1536 blocks
    lr_expand_kernel<<<g2, 256, 0, stream>>>(x, notepitch, cum, out, pitch_out);
}

// Round 4
// 351.827 us; speedup vs baseline: 1.1278x; 1.0036x over previous
//
#include <hip/hip_runtime.h>

#define BB 32
#define CC 384
#define TT 512
#define MAXF 6656      // T * 13
#define CG 8           // channels per block
#define NCHUNK 7       // ceil(6656 / 1024), last chunk is half

// ---------------- Kernel 1: repeat counts + inclusive scan ----------------
__global__ void lr_scan_kernel(const float* __restrict__ duration,
                               int* __restrict__ cum,
                               float* __restrict__ fl_out) {
    __shared__ int buf[TT];
    const int b = blockIdx.x;
    const int t = threadIdx.x;
    const float d = duration[b * TT + t];
    const float fr = 44100.0f * d;
    float rf;
    if (fr - 1024.0f > 0.0f) {
        rf = fmaxf((fr - 1024.0f) * (1.0f / 256.0f), 1.0f);
    } else {
        rf = (d == 0.0f) ? 0.0f : 1.0f;
    }
    buf[t] = (int)rf;   // truncation toward zero, matches astype(int32)
    __syncthreads();
    for (int off = 1; off < TT; off <<= 1) {
        int add = (t >= off) ? buf[t - off] : 0;
        __syncthreads();
        buf[t] += add;
        __syncthreads();
    }
    cum[b * TT + t] = buf[t];
    if (t == TT - 1) fl_out[b] = (float)buf[t];
}

// ---------------- Kernel 2: fused expand + pitch ----------------
// grid = (CC/CG, BB), 256 threads. Block stages cum + 8 x-rows in LDS,
// scatter-inverts cum -> per-frame token id (ushort) ONCE, then streams
// stores with a block-uniform 3-way chunk classification vs fl:
//   zero chunk  : no gathers, no masks (E[fl]~2700 of 6656 -> ~60% of frames)
//   valid chunk : unmasked gathers
//   mixed chunk : clamp + cndmask (at most one per row)
__global__ __launch_bounds__(256) void lr_expand_kernel(
        const float* __restrict__ x,
        const float* __restrict__ notepitch,
        const int* __restrict__ cum,
        float* __restrict__ out,
        float* __restrict__ pitch_out) {
    __shared__ int   scum[TT];
    __shared__ float xs[CG * TT];
    __shared__ float snp[TT];
    __shared__ __attribute__((aligned(16))) unsigned short stok[MAXF];  // 13 KB

    const int b   = blockIdx.y;
    const int cg  = blockIdx.x;
    const int tid = threadIdx.x;
    const bool do_pitch = (cg == 0);

    for (int i = tid; i < TT; i += 256) scum[i] = cum[b * TT + i];
    {
        const float4* src = (const float4*)(x + ((size_t)(b * CC + cg * CG)) * TT);
        float4* dst = (float4*)xs;
        #pragma unroll
        for (int i = 0; i < (CG * TT / 4) / 256; ++i)
            dst[i * 256 + tid] = src[i * 256 + tid];
    }
    if (do_pitch)
        for (int i = tid; i < TT; i += 256) snp[i] = notepitch[b * TT + i];
    __syncthreads();

    const int fl = scum[TT - 1];

    // Scatter inversion: token t owns frames [scum[t-1], scum[t)).
    // Covers exactly [0, fl); frames >= fl are never gathered (zero path),
    // except the mixed chunk which clamps garbage indices before masking.
    #pragma unroll
    for (int k = 0; k < TT / 256; ++k) {
        const int t = k * 256 + tid;
        const int s = (t == 0) ? 0 : scum[t - 1];
        const int e = scum[t];
        for (int f = s; f < e; ++f) stok[f] = (unsigned short)t;
    }
    __syncthreads();

    float* const obase = out + ((size_t)(b * CC + cg * CG)) * MAXF;

    for (int ch = 0; ch < NCHUNK; ++ch) {
        const int base = ch * 1024;
        const int p0 = base + tid * 4;
        if (p0 >= MAXF) continue;   // only chunk 6, tid >= 128

        if (base >= fl) {
            // ---- pure zero chunk (block-uniform branch) ----
            const float4 z = make_float4(0.f, 0.f, 0.f, 0.f);
            #pragma unroll
            for (int c = 0; c < CG; ++c)
                *(float4*)(obase + (size_t)c * MAXF + p0) = z;
            if (do_pitch)
                *(float4*)(pitch_out + (size_t)b * MAXF + p0) = z;
        } else if (base + 1024 <= fl) {
            // ---- fully valid chunk: unmasked gathers ----
            const ushort4 tk = *(const ushort4*)(stok + p0);
            const int u0 = tk.x, u1 = tk.y, u2 = tk.z, u3 = tk.w;
            #pragma unroll
            for (int c = 0; c < CG; ++c) {
                const float* xr = xs + c * TT;
                float4 v = make_float4(xr[u0], xr[u1], xr[u2], xr[u3]);
                *(float4*)(obase + (size_t)c * MAXF + p0) = v;
            }
            if (do_pitch) {
                float4 pv = make_float4((float)(int)snp[u0], (float)(int)snp[u1],
                                        (float)(int)snp[u2], (float)(int)snp[u3]);
                *(float4*)(pitch_out + (size_t)b * MAXF + p0) = pv;
            }
        } else {
            // ---- mixed chunk: clamp garbage tokens, mask tail ----
            const ushort4 tk = *(const ushort4*)(stok + p0);
            const int u0 = min((int)tk.x, TT - 1), u1 = min((int)tk.y, TT - 1);
            const int u2 = min((int)tk.z, TT - 1), u3 = min((int)tk.w, TT - 1);
            const bool m0 = p0 < fl, m1 = p0 + 1 < fl;
            const bool m2 = p0 + 2 < fl, m3 = p0 + 3 < fl;
            #pragma unroll
            for (int c = 0; c < CG; ++c) {
                const float* xr = xs + c * TT;
                float4 v;
                v.x = m0 ? xr[u0] : 0.f;
                v.y = m1 ? xr[u1] : 0.f;
                v.z = m2 ? xr[u2] : 0.f;
                v.w = m3 ? xr[u3] : 0.f;
                *(float4*)(obase + (size_t)c * MAXF + p0) = v;
            }
            if (do_pitch) {
                float4 pv;
                pv.x = m0 ? (float)(int)snp[u0] : 0.f;
                pv.y = m1 ? (float)(int)snp[u1] : 0.f;
                pv.z = m2 ? (float)(int)snp[u2] : 0.f;
                pv.w = m3 ? (float)(int)snp[u3] : 0.f;
                *(float4*)(pitch_out + (size_t)b * MAXF + p0) = pv;
            }
        }
    }
}

extern "C" void kernel_launch(void* const* d_in, const int* in_sizes, int n_in,
                              void* d_out, int out_size, void* d_ws, size_t ws_size,
                              hipStream_t stream) {
    const float* x         = (const float*)d_in[0];  // (B, C, T)
    const float* notepitch = (const float*)d_in[1];  // (B, T)
    const float* duration  = (const float*)d_in[2];  // (B, T)
    // d_in[3] = x_lengths — unused by the reference computation

    float* out       = (float*)d_out;                       // (B, C, MAXF)
    float* pitch_out = out + (size_t)BB * CC * MAXF;        // (B, MAXF)
    float* fl_out    = pitch_out + (size_t)BB * MAXF;       // (B,)

    int* cum = (int*)d_ws;   // B*T ints = 64 KB

    lr_scan_kernel<<<BB, TT, 0, stream>>>(duration, cum, fl_out);

    dim3 g2(CC / CG, BB);    // 48 x 32 = 1536 blocks
    lr_expand_kernel<<<g2, 256, 0, stream>>>(x, notepitch, cum, out, pitch_out);
}

// Round 5
// 350.971 us; speedup vs baseline: 1.1305x; 1.0024x over previous
//
#include <hip/hip_runtime.h>

#define BB 32
#define CC 384
#define TT 512
#define MAXF 6656      // T * 13
#define CG 8           // channels per block
#define NCHUNK 7       // ceil(6656 / 1024), last chunk is half

// Single fused kernel. grid = (CC/CG, BB), 256 threads.
// Per block: issue x-row loads -> in-block repeat-count scan (replicated, cheap)
// -> zero-region stores (need only fl) -> stok scatter -> valid/mixed stores.
__global__ __launch_bounds__(256) void lr_fused_kernel(
        const float* __restrict__ x,
        const float* __restrict__ notepitch,
        const float* __restrict__ duration,
        float* __restrict__ out,
        float* __restrict__ pitch_out,
        float* __restrict__ fl_out) {
    __shared__ float xs[CG * TT];                                   // 16 KB
    __shared__ float snp[TT];                                       // 2 KB
    __shared__ int   sbuf[256];                                     // 1 KB
    __shared__ __attribute__((aligned(16))) unsigned short stok[MAXF]; // 13 KB

    const int b   = blockIdx.y;
    const int cg  = blockIdx.x;
    const int tid = threadIdx.x;
    const bool do_pitch = (cg == 0);

    // ---- issue x staging loads first (latency overlapped with scan) ----
    const float4* xsrc = (const float4*)(x + ((size_t)(b * CC + cg * CG)) * TT);
    const float4 xa0 = xsrc[tid];
    const float4 xa1 = xsrc[256 + tid];
    const float4 xa2 = xsrc[512 + tid];
    const float4 xa3 = xsrc[768 + tid];
    float2 np2 = make_float2(0.f, 0.f);
    if (do_pitch) np2 = *(const float2*)(notepitch + b * TT + 2 * tid);

    // ---- repeat counts for tokens 2*tid, 2*tid+1 ----
    const float2 dp = *(const float2*)(duration + b * TT + 2 * tid);
    int r0, r1;
    {
        float fr = 44100.0f * dp.x, rf;
        if (fr - 1024.0f > 0.0f) rf = fmaxf((fr - 1024.0f) * (1.0f / 256.0f), 1.0f);
        else rf = (dp.x == 0.0f) ? 0.0f : 1.0f;
        r0 = (int)rf;
        fr = 44100.0f * dp.y;
        if (fr - 1024.0f > 0.0f) rf = fmaxf((fr - 1024.0f) * (1.0f / 256.0f), 1.0f);
        else rf = (dp.y == 0.0f) ? 0.0f : 1.0f;
        r1 = (int)rf;
    }
    const int s = r0 + r1;

    // ---- inclusive scan of 256 pair-sums (Hillis-Steele in LDS) ----
    sbuf[tid] = s;
    __syncthreads();
    for (int off = 1; off < 256; off <<= 1) {
        const int add = (tid >= off) ? sbuf[tid - off] : 0;
        __syncthreads();
        sbuf[tid] += add;
        __syncthreads();
    }
    const int incl = sbuf[tid];      // inclusive over pairs -> cum[2*tid+1]
    const int excl = incl - s;       // exclusive -> start frame of token 2*tid
    const int fl   = sbuf[255];      // frame_lengths[b]

    if (do_pitch && tid == 0) fl_out[b] = (float)fl;

    // ---- stage x rows / pitch into LDS (loads already in flight) ----
    {
        float4* xdst = (float4*)xs;
        xdst[tid] = xa0; xdst[256 + tid] = xa1;
        xdst[512 + tid] = xa2; xdst[768 + tid] = xa3;
    }
    if (do_pitch) *(float2*)(snp + 2 * tid) = np2;

    float* const obase = out + ((size_t)(b * CC + cg * CG)) * MAXF;
    const float4 z = make_float4(0.f, 0.f, 0.f, 0.f);

    // ---- phase 1: pure zero chunks (need only fl, not stok) ----
    #pragma unroll
    for (int ch = 0; ch < NCHUNK; ++ch) {
        const int base = ch * 1024;
        const int p0 = base + tid * 4;
        if (base >= fl && p0 < MAXF) {
            #pragma unroll
            for (int c = 0; c < CG; ++c)
                *(float4*)(obase + (size_t)c * MAXF + p0) = z;
            if (do_pitch)
                *(float4*)(pitch_out + (size_t)b * MAXF + p0) = z;
        }
    }

    // ---- scatter inversion: token t owns frames [excl_t, excl_t + r_t) ----
    for (int f = excl; f < excl + r0; ++f)       stok[f] = (unsigned short)(2 * tid);
    for (int f = excl + r0; f < incl; ++f)       stok[f] = (unsigned short)(2 * tid + 1);
    __syncthreads();

    // ---- phase 2: valid / mixed chunks ----
    for (int ch = 0; ch < NCHUNK; ++ch) {
        const int base = ch * 1024;
        const int p0 = base + tid * 4;
        if (base >= fl || p0 >= MAXF) continue;

        if (base + 1024 <= fl) {
            // fully valid: unmasked gathers
            const ushort4 tk = *(const ushort4*)(stok + p0);
            const int u0 = tk.x, u1 = tk.y, u2 = tk.z, u3 = tk.w;
            #pragma unroll
            for (int c = 0; c < CG; ++c) {
                const float* xr = xs + c * TT;
                *(float4*)(obase + (size_t)c * MAXF + p0) =
                    make_float4(xr[u0], xr[u1], xr[u2], xr[u3]);
            }
            if (do_pitch)
                *(float4*)(pitch_out + (size_t)b * MAXF + p0) =
                    make_float4((float)(int)snp[u0], (float)(int)snp[u1],
                                (float)(int)snp[u2], (float)(int)snp[u3]);
        } else {
            // mixed: clamp garbage tokens (stok uninit beyond fl), mask tail
            const ushort4 tk = *(const ushort4*)(stok + p0);
            const int u0 = min((int)tk.x, TT - 1), u1 = min((int)tk.y, TT - 1);
            const int u2 = min((int)tk.z, TT - 1), u3 = min((int)tk.w, TT - 1);
            const bool m0 = p0 < fl, m1 = p0 + 1 < fl;
            const bool m2 = p0 + 2 < fl, m3 = p0 + 3 < fl;
            #pragma unroll
            for (int c = 0; c < CG; ++c) {
                const float* xr = xs + c * TT;
                float4 v;
                v.x = m0 ? xr[u0] : 0.f;
                v.y = m1 ? xr[u1] : 0.f;
                v.z = m2 ? xr[u2] : 0.f;
                v.w = m3 ? xr[u3] : 0.f;
                *(float4*)(obase + (size_t)c * MAXF + p0) = v;
            }
            if (do_pitch) {
                float4 pv;
                pv.x = m0 ? (float)(int)snp[u0] : 0.f;
                pv.y = m1 ? (float)(int)snp[u1] : 0.f;
                pv.z = m2 ? (float)(int)snp[u2] : 0.f;
                pv.w = m3 ? (float)(int)snp[u3] : 0.f;
                *(float4*)(pitch_out + (size_t)b * MAXF + p0) = pv;
            }
        }
    }
}

extern "C" void kernel_launch(void* const* d_in, const int* in_sizes, int n_in,
                              void* d_out, int out_size, void* d_ws, size_t ws_size,
                              hipStream_t stream) {
    const float* x         = (const float*)d_in[0];  // (B, C, T)
    const float* notepitch = (const float*)d_in[1];  // (B, T)
    const float* duration  = (const float*)d_in[2];  // (B, T)
    // d_in[3] = x_lengths — unused by the reference computation

    float* out       = (float*)d_out;                    // (B, C, MAXF)
    float* pitch_out = out + (size_t)BB * CC * MAXF;     // (B, MAXF)
    float* fl_out    = pitch_out + (size_t)BB * MAXF;    // (B,)

    dim3 g(CC / CG, BB);   // 48 x 32 = 1536 blocks
    lr_fused_kernel<<<g, 256, 0, stream>>>(x, notepitch, duration,
                                           out, pitch_out, fl_out);
}